// Round 7
// baseline (12780.393 us; speedup 1.0000x reference)
//
// R7: persistent bi-LSTM scan (1 kernel per layer, was 256 launches/layer).
// Manual inter-block barrier via agent-scope atomics (cooperative API broken in
// this harness, R2/R3). Grid 128 blocks <= 256 CUs -> co-residency guaranteed
// by capacity; bounded spin + abort flag turns any hang into fast-fail.
// Block = (dir, 8 h-cols): U slice 512x32 fp16 persistent in 128 VGPRs; h tile
// LDS w/ row-XOR swizzle; MFMA 16x16x32_f16; c/h state in registers (cbuf slot
// reused for barrier counters -> footprint stays at R4-proven 168,955,904 B).
#include <hip/hip_runtime.h>
#include <hip/hip_fp16.h>
#include <math.h>

#define NB   64
#define NS   256
#define ND   300
#define NDP  320
#define NH   512
#define N4H  2048

typedef _Float16 half8_t __attribute__((ext_vector_type(8)));
typedef float    f32x4_t __attribute__((ext_vector_type(4)));

// ---------- embedding: gather + fp16 convert + zero-pad K to 320 ----------
__global__ void embed_f16_kernel(const int* __restrict__ text,
                                 const float* __restrict__ emb,
                                 _Float16* __restrict__ x) {
  int idx = blockIdx.x * 256 + threadIdx.x;
  const int total = NB * NS * NDP;
  for (; idx < total; idx += gridDim.x * 256) {
    int bs = idx / NDP;
    int d  = idx - bs * NDP;
    x[idx] = (d < ND) ? (_Float16)emb[(size_t)text[bs] * ND + d] : (_Float16)0.f;
  }
}

// ---------- MFMA GEMM with in-LDS weight transpose (unchanged from R6) ----------
__global__ __launch_bounds__(256) void gemm_mfma_kernel(
    const _Float16* __restrict__ A, const float* __restrict__ W,
    const float* __restrict__ bias, __half* __restrict__ C,
    int M, int N, int K, int Kw) {
  __shared__ __align__(16) _Float16 as[128][40];
  __shared__ __align__(16) _Float16 ws16[128][40];
  __shared__ __align__(16) float    ws32[32][132];
  const int t = threadIdx.x;
  const int w = t >> 6;
  const int l = t & 63;
  const int lane16 = l & 15;
  const int kq = l >> 4;
  const int bm = blockIdx.y * 128;
  const int bn = blockIdx.x * 128;
  const int lr  = t >> 2;
  const int lsg = t & 3;
  const int wk  = t >> 3;
  const int wns = t & 7;
  const int rn  = t >> 1;
  const int rk0 = (t & 1) * 2;

  f32x4_t acc[2][8];
#pragma unroll
  for (int i = 0; i < 2; i++)
#pragma unroll
    for (int j = 0; j < 8; j++) acc[i][j] = (f32x4_t){0.f, 0.f, 0.f, 0.f};

  for (int k0 = 0; k0 < K; k0 += 32) {
#pragma unroll
    for (int h = 0; h < 2; h++) {
      int m = h * 64 + lr;
      *(uint4*)&as[m][lsg * 8] = *(const uint4*)(A + (size_t)(bm + m) * K + k0 + lsg * 8);
    }
    if (k0 + wk < Kw) {
#pragma unroll
      for (int i = 0; i < 4; i++)
        *(float4*)&ws32[wk][wns * 16 + i * 4] =
            *(const float4*)(W + (size_t)(k0 + wk) * N + bn + wns * 16 + i * 4);
    } else {
#pragma unroll
      for (int i = 0; i < 4; i++)
        *(float4*)&ws32[wk][wns * 16 + i * 4] = make_float4(0.f, 0.f, 0.f, 0.f);
    }
    __syncthreads();
#pragma unroll
    for (int g = 0; g < 2; g++) {
      int kqq = rk0 + g;
      half8_t hv;
#pragma unroll
      for (int jj = 0; jj < 8; jj++) hv[jj] = (_Float16)ws32[kqq * 8 + jj][rn];
      *(half8_t*)&ws16[rn][kqq * 8] = hv;
    }
    __syncthreads();
    half8_t afrag[2];
#pragma unroll
    for (int i = 0; i < 2; i++)
      afrag[i] = *(const half8_t*)&as[w * 32 + i * 16 + lane16][kq * 8];
#pragma unroll
    for (int j = 0; j < 8; j++) {
      half8_t bfrag = *(const half8_t*)&ws16[j * 16 + lane16][kq * 8];
#pragma unroll
      for (int i = 0; i < 2; i++)
        acc[i][j] = __builtin_amdgcn_mfma_f32_16x16x32_f16(afrag[i], bfrag, acc[i][j], 0, 0, 0);
    }
    __syncthreads();
  }
#pragma unroll
  for (int j = 0; j < 8; j++) {
    int col = bn + j * 16 + lane16;
    float bv = bias[col];
#pragma unroll
    for (int i = 0; i < 2; i++) {
      int rbase = bm + w * 32 + i * 16 + kq * 4;
#pragma unroll
      for (int r = 0; r < 4; r++)
        C[(size_t)(rbase + r) * N + col] = __float2half(acc[i][j][r] + bv);
    }
  }
}

// ---------- persistent bi-LSTM scan ----------
// Grid MUST be 128 x 256. Block bi = dir*64 + cblk; owns h-cols [cblk*8, +8)
// of its direction (32 z-cols, full K=512). Barrier: cnt[dir*256+s] arrival
// counter (expect 64), agent-scope release/acquire. h ping-pong h0buf/h1buf
// (64 x 1024 fp16: fwd [0,512) bwd [512,1024)). c/h state in registers.
__global__ __launch_bounds__(256, 1) void scan_persist_kernel(
    const __half* __restrict__ xzf, const __half* __restrict__ xzb,
    const float* __restrict__ Uf, const float* __restrict__ Ub,
    const int* __restrict__ text,
    __half* __restrict__ h0buf, __half* __restrict__ h1buf,
    int* __restrict__ cnt, int* __restrict__ abortf,
    __half* __restrict__ hs_out, float* __restrict__ hT_out) {
  __shared__ __align__(16) char lds[65536];
  __shared__ int s_brk;
  _Float16* s_h = (_Float16*)lds;   // [64][512] fp16, chunk-XOR swizzle
  float*    s_z = (float*)lds;      // [64][33] fp32 overlay

  const int t    = threadIdx.x;
  const int bi   = blockIdx.x;
  const int dir  = bi >> 6;
  const int cblk = bi & 63;
  const int hc0  = cblk * 8;
  const __half* xz = dir ? xzb : xzf;
  const float* U = dir ? Ub : Uf;
  int* mycnt = cnt + dir * NS;

  const int w    = t >> 6;          // wave = m-tile (rows w*16..w*16+16)
  const int lane = t & 63;
  const int l16  = lane & 15;
  const int quad = lane >> 4;

  // persistent U B-frags: ufrag[kt][nt] = U[k=kt*32+quad*8+jj][col(nt,l16)] fp16
  half8_t ufrag[16][2];
#pragma unroll
  for (int nt = 0; nt < 2; nt++) {
    int c = nt * 16 + l16;
    int col = (c >> 3) * NH + hc0 + (c & 7);
#pragma unroll
    for (int kt = 0; kt < 16; kt++)
#pragma unroll
      for (int jj = 0; jj < 8; jj++)
        ufrag[kt][nt][jj] = (_Float16)U[(size_t)(kt * 32 + quad * 8 + jj) * N4H + col];
  }

  // LSTM state: idx = u*256+t -> (row = idx>>3, j = idx&7)
  float c_st[2] = {0.f, 0.f}, h_st[2] = {0.f, 0.f};

  for (int s = 0; s < NS; s++) {
    const int tt = dir ? (NS - 1 - s) : s;
    __half* hw       = (s & 1) ? h1buf : h0buf;
    const __half* hr = (s & 1) ? h0buf : h1buf;
    f32x4_t acc[2] = {{0.f, 0.f, 0.f, 0.f}, {0.f, 0.f, 0.f, 0.f}};

    if (s > 0) {
      // stage h(s-1): rows 0..63 x 512 fp16; 16B chunk ch stored at ch^row
#pragma unroll
      for (int i = 0; i < 16; i++) {
        int e   = i * 256 + t;
        int row = e >> 6;
        int ch  = e & 63;
        *(uint4*)(s_h + row * 512 + (ch ^ row) * 8) =
            *(const uint4*)(hr + (size_t)row * 1024 + dir * NH + ch * 8);
      }
      __syncthreads();
#pragma unroll
      for (int kt = 0; kt < 16; kt++) {
        int r = w * 16 + l16;
        int chunk = (kt * 4 + quad) ^ r;
        half8_t af = *(const half8_t*)(s_h + r * 512 + chunk * 8);
        acc[0] = __builtin_amdgcn_mfma_f32_16x16x32_f16(af, ufrag[kt][0], acc[0], 0, 0, 0);
        acc[1] = __builtin_amdgcn_mfma_f32_16x16x32_f16(af, ufrag[kt][1], acc[1], 0, 0, 0);
      }
      __syncthreads();   // all s_h reads done before s_z overlay
    }

    // dump z = acc + xz into LDS z[64][33]
    {
      int row0 = w * 16 + quad * 4;
#pragma unroll
      for (int nt = 0; nt < 2; nt++) {
        int c = nt * 16 + l16;
        int g = c >> 3, j = c & 7;
#pragma unroll
        for (int r = 0; r < 4; r++) {
          int row = row0 + r;
          float xzv = __half2float(xz[((size_t)row * NS + tt) * N4H + g * NH + hc0 + j]);
          s_z[row * 33 + c] = acc[nt][r] + xzv;
        }
      }
    }
    __syncthreads();

    // gate update: 2 states per thread
#pragma unroll
    for (int u = 0; u < 2; u++) {
      int idx = u * 256 + t;
      int row = idx >> 3, j = idx & 7;
      float zi = s_z[row * 33 + j];
      float zf = s_z[row * 33 + 8 + j];
      float zg = s_z[row * 33 + 16 + j];
      float zo = s_z[row * 33 + 24 + j];
      float ig = 1.f / (1.f + expf(-zi));
      float fg = 1.f / (1.f + expf(-zf));
      float gv = tanhf(zg);
      float og = 1.f / (1.f + expf(-zo));
      float cn = fg * c_st[u] + ig * gv;
      float hn = og * tanhf(cn);
      if (text[row * NS + tt] != 0) { c_st[u] = cn; h_st[u] = hn; }
      hw[(size_t)row * 1024 + dir * NH + hc0 + j] = __float2half(h_st[u]);
      if (hs_out)
        hs_out[((size_t)row * NS + tt) * 1024 + dir * NH + hc0 + j] = __float2half(h_st[u]);
      if (hT_out && s == NS - 1)
        hT_out[(size_t)row * 1024 + dir * NH + hc0 + j] = h_st[u];
    }

    if (s < NS - 1) {
      __threadfence();      // agent-scope visibility of h stores
      __syncthreads();      // all stores issued + all s_z reads done
      if (t == 0) {
        __hip_atomic_fetch_add(mycnt + s, 1, __ATOMIC_RELEASE, __HIP_MEMORY_SCOPE_AGENT);
        int it = 0;
        while (__hip_atomic_load(mycnt + s, __ATOMIC_ACQUIRE, __HIP_MEMORY_SCOPE_AGENT) < 64) {
          __builtin_amdgcn_s_sleep(2);
          if (((++it) & 2047) == 0) {
            if (it > 8000000)
              __hip_atomic_store(abortf, 1, __ATOMIC_RELAXED, __HIP_MEMORY_SCOPE_AGENT);
            if (__hip_atomic_load(abortf, __ATOMIC_RELAXED, __HIP_MEMORY_SCOPE_AGENT)) break;
          }
        }
        s_brk = __hip_atomic_load(abortf, __ATOMIC_RELAXED, __HIP_MEMORY_SCOPE_AGENT);
      }
      __syncthreads();      // barrier passed; also protects s_h rewrite next iter
      if (s_brk) return;    // fast-fail instead of hang
    }
  }
}

// ---------- fp32 SMEM GEMM (head only) ----------
template <int ACT>
__global__ __launch_bounds__(256) void gemm_kernel(
    const float* __restrict__ A, const float* __restrict__ W,
    const float* __restrict__ bias, float* __restrict__ C,
    int M, int N, int K) {
  __shared__ __align__(16) float As[8][128];
  __shared__ __align__(16) float Bs[8][128];
  const int t  = threadIdx.x;
  const int bn = blockIdx.x * 128;
  const int bm = blockIdx.y * 128;
  const int tx = t & 15, ty = t >> 4;
  const int lm  = t >> 1;
  const int lk4 = (t & 1) * 4;
  const int lbk = t >> 5;
  const int lbn = (t & 31) * 4;
  float acc[8][8];
#pragma unroll
  for (int i = 0; i < 8; i++)
#pragma unroll
    for (int j = 0; j < 8; j++) acc[i][j] = 0.f;

  for (int k0 = 0; k0 < K; k0 += 8) {
#pragma unroll
    for (int i = 0; i < 4; i++) {
      int k = k0 + lk4 + i;
      int m = bm + lm;
      float v = 0.f;
      if (k < K && m < M) v = A[(size_t)m * K + k];
      As[lk4 + i][lm] = v;
    }
    {
      int k = k0 + lbk;
      float4 v = make_float4(0.f, 0.f, 0.f, 0.f);
      if (k < K) v = *(const float4*)(W + (size_t)k * N + bn + lbn);
      *(float4*)(&Bs[lbk][lbn]) = v;
    }
    __syncthreads();
#pragma unroll
    for (int kk = 0; kk < 8; kk++) {
      float a[8], b[8];
      *(float4*)(a)     = *(const float4*)(&As[kk][ty * 8]);
      *(float4*)(a + 4) = *(const float4*)(&As[kk][ty * 8 + 4]);
      *(float4*)(b)     = *(const float4*)(&Bs[kk][tx * 8]);
      *(float4*)(b + 4) = *(const float4*)(&Bs[kk][tx * 8 + 4]);
#pragma unroll
      for (int i = 0; i < 8; i++)
#pragma unroll
        for (int j = 0; j < 8; j++) acc[i][j] += a[i] * b[j];
    }
    __syncthreads();
  }
  float4 bv0 = *(const float4*)(bias + bn + tx * 8);
  float4 bv1 = *(const float4*)(bias + bn + tx * 8 + 4);
#pragma unroll
  for (int i = 0; i < 8; i++) {
    int m = bm + ty * 8 + i;
    if (m >= M) continue;
    float4 o0, o1;
    o0.x = acc[i][0] + bv0.x; o0.y = acc[i][1] + bv0.y;
    o0.z = acc[i][2] + bv0.z; o0.w = acc[i][3] + bv0.w;
    o1.x = acc[i][4] + bv1.x; o1.y = acc[i][5] + bv1.y;
    o1.z = acc[i][6] + bv1.z; o1.w = acc[i][7] + bv1.w;
    if (ACT == 1) {
      o0.x = o0.x >= 0.f ? o0.x : 0.2f * o0.x;  o0.y = o0.y >= 0.f ? o0.y : 0.2f * o0.y;
      o0.z = o0.z >= 0.f ? o0.z : 0.2f * o0.z;  o0.w = o0.w >= 0.f ? o0.w : 0.2f * o0.w;
      o1.x = o1.x >= 0.f ? o1.x : 0.2f * o1.x;  o1.y = o1.y >= 0.f ? o1.y : 0.2f * o1.y;
      o1.z = o1.z >= 0.f ? o1.z : 0.2f * o1.z;  o1.w = o1.w >= 0.f ? o1.w : 0.2f * o1.w;
    }
    *(float4*)(C + (size_t)m * N + bn + tx * 8)     = o0;
    *(float4*)(C + (size_t)m * N + bn + tx * 8 + 4) = o1;
  }
}

__global__ void final_kernel(const float* __restrict__ a1, const float* __restrict__ w,
                             const float* __restrict__ bias, float* __restrict__ out) {
  const int b = blockIdx.x, t = threadIdx.x;
  float v = a1[b * 256 + t] * w[t];
#pragma unroll
  for (int off = 32; off > 0; off >>= 1) v += __shfl_down(v, off, 64);
  __shared__ float red[4];
  if ((t & 63) == 0) red[t >> 6] = v;
  __syncthreads();
  if (t == 0) out[b] = (red[0] + red[1]) + (red[2] + red[3]) + bias[0];
}

extern "C" void kernel_launch(void* const* d_in, const int* in_sizes, int n_in,
                              void* d_out, int out_size, void* d_ws, size_t ws_size,
                              hipStream_t stream) {
  const int*   text = (const int*)  d_in[0];
  const float* emb  = (const float*)d_in[1];
  const float* W0f  = (const float*)d_in[2];
  const float* U0f  = (const float*)d_in[3];
  const float* b0f  = (const float*)d_in[4];
  const float* W0b  = (const float*)d_in[5];
  const float* U0b  = (const float*)d_in[6];
  const float* b0b  = (const float*)d_in[7];
  const float* W1f  = (const float*)d_in[8];
  const float* U1f  = (const float*)d_in[9];
  const float* b1f  = (const float*)d_in[10];
  const float* W1b  = (const float*)d_in[11];
  const float* U1b  = (const float*)d_in[12];
  const float* b1b  = (const float*)d_in[13];
  const float* d0w  = (const float*)d_in[14];
  const float* d0b  = (const float*)d_in[15];
  const float* d1w  = (const float*)d_in[16];
  const float* d1b  = (const float*)d_in[17];
  const float* d2w  = (const float*)d_in[18];
  const float* d2b  = (const float*)d_in[19];
  float* out = (float*)d_out;

  // workspace carve: identical to R4/R6 footprint (168,955,904 B)
  char* p = (char*)d_ws;
  __half* xzA = (__half*)p;  p += (size_t)NB * NS * N4H * 2;
  __half* xzB = (__half*)p;  p += (size_t)NB * NS * N4H * 2;
  char* region1 = p;         p += (size_t)NB * NS * 1024 * 2;
  _Float16* x_emb = (_Float16*)region1;   // dead before hs0 written
  __half*   hs0   = (__half*)region1;
  __half* hp0  = (__half*)p;  p += 64 * 1024 * 2;
  __half* hp1  = (__half*)p;  p += 64 * 1024 * 2;
  int*    cnt  = (int*)p;     p += 64 * 1024 * 4;   // old cbuf slot: counters+abort
  float*  feat = (float*)p;   p += 64 * 1024 * 4;
  float*  a0   = (float*)p;   p += 64 * 512 * 4;
  float*  a1   = (float*)p;   p += 64 * 256 * 4;
  int* cnt0   = cnt;          // layer0: [dir*256 + s]
  int* cnt1   = cnt + 512;    // layer1
  int* abortf = cnt + 1024;

  hipMemsetAsync(cnt, 0, 1025 * sizeof(int), stream);
  hipLaunchKernelGGL(embed_f16_kernel, dim3(4096), dim3(256), 0, stream, text, emb, x_emb);

  dim3 gmf(16, 128);
  hipLaunchKernelGGL(gemm_mfma_kernel, gmf, dim3(256), 0, stream, x_emb, W0f, b0f, xzA, 16384, N4H, NDP, ND);
  hipLaunchKernelGGL(gemm_mfma_kernel, gmf, dim3(256), 0, stream, x_emb, W0b, b0b, xzB, 16384, N4H, NDP, ND);

  hipLaunchKernelGGL(scan_persist_kernel, dim3(128), dim3(256), 0, stream,
                     xzA, xzB, U0f, U0b, text, hp0, hp1, cnt0, abortf,
                     hs0, (float*)nullptr);

  hipLaunchKernelGGL(gemm_mfma_kernel, gmf, dim3(256), 0, stream, (const _Float16*)hs0, W1f, b1f, xzA, 16384, N4H, 1024, 1024);
  hipLaunchKernelGGL(gemm_mfma_kernel, gmf, dim3(256), 0, stream, (const _Float16*)hs0, W1b, b1b, xzB, 16384, N4H, 1024, 1024);

  hipLaunchKernelGGL(scan_persist_kernel, dim3(128), dim3(256), 0, stream,
                     xzA, xzB, U1f, U1b, text, hp0, hp1, cnt1, abortf,
                     (__half*)nullptr, feat);

  gemm_kernel<1><<<dim3(4, 1), dim3(256), 0, stream>>>(feat, d0w, d0b, a0, 64, 512, 1024);
  gemm_kernel<1><<<dim3(2, 1), dim3(256), 0, stream>>>(a0, d1w, d1b, a1, 64, 256, 512);
  hipLaunchKernelGGL(final_kernel, dim3(64), dim3(256), 0, stream, a1, d2w, d2b, out);
}

// Round 8
// 6731.007 us; speedup vs baseline: 1.8987x; 1.8987x over previous
//
// R8: drop in-kernel barrier (R7 post-mortem: agent-scope acquire/release =
// per-poll L2 invalidate + per-step L2 writeback on non-coherent XCD L2s ->
// 695MB FETCH/dispatch, 23us/step). Back to R6 per-step launches with an
// MFMA step kernel: 128 blocks=(dir, 8 h-cols), all 64 rows, K=512 in-block;
// U staged 1x (8MB/step, was 64MB) fp32->fp16 into LDS; h tile XOR-swizzled;
// c-state in global cbuf. GEMMs/embed/head unchanged from R6 (passed).
#include <hip/hip_runtime.h>
#include <hip/hip_fp16.h>
#include <math.h>

#define NB   64
#define NS   256
#define ND   300
#define NDP  320
#define NH   512
#define N4H  2048

typedef _Float16 half8_t __attribute__((ext_vector_type(8)));
typedef float    f32x4_t __attribute__((ext_vector_type(4)));

// ---------- embedding: gather + fp16 convert + zero-pad K to 320 ----------
__global__ void embed_f16_kernel(const int* __restrict__ text,
                                 const float* __restrict__ emb,
                                 _Float16* __restrict__ x) {
  int idx = blockIdx.x * 256 + threadIdx.x;
  const int total = NB * NS * NDP;
  for (; idx < total; idx += gridDim.x * 256) {
    int bs = idx / NDP;
    int d  = idx - bs * NDP;
    x[idx] = (d < ND) ? (_Float16)emb[(size_t)text[bs] * ND + d] : (_Float16)0.f;
  }
}

// ---------- MFMA GEMM with in-LDS weight transpose (unchanged from R6) ----------
__global__ __launch_bounds__(256) void gemm_mfma_kernel(
    const _Float16* __restrict__ A, const float* __restrict__ W,
    const float* __restrict__ bias, __half* __restrict__ C,
    int M, int N, int K, int Kw) {
  __shared__ __align__(16) _Float16 as[128][40];
  __shared__ __align__(16) _Float16 ws16[128][40];
  __shared__ __align__(16) float    ws32[32][132];
  const int t = threadIdx.x;
  const int w = t >> 6;
  const int l = t & 63;
  const int lane16 = l & 15;
  const int kq = l >> 4;
  const int bm = blockIdx.y * 128;
  const int bn = blockIdx.x * 128;
  const int lr  = t >> 2;
  const int lsg = t & 3;
  const int wk  = t >> 3;
  const int wns = t & 7;
  const int rn  = t >> 1;
  const int rk0 = (t & 1) * 2;

  f32x4_t acc[2][8];
#pragma unroll
  for (int i = 0; i < 2; i++)
#pragma unroll
    for (int j = 0; j < 8; j++) acc[i][j] = (f32x4_t){0.f, 0.f, 0.f, 0.f};

  for (int k0 = 0; k0 < K; k0 += 32) {
#pragma unroll
    for (int h = 0; h < 2; h++) {
      int m = h * 64 + lr;
      *(uint4*)&as[m][lsg * 8] = *(const uint4*)(A + (size_t)(bm + m) * K + k0 + lsg * 8);
    }
    if (k0 + wk < Kw) {
#pragma unroll
      for (int i = 0; i < 4; i++)
        *(float4*)&ws32[wk][wns * 16 + i * 4] =
            *(const float4*)(W + (size_t)(k0 + wk) * N + bn + wns * 16 + i * 4);
    } else {
#pragma unroll
      for (int i = 0; i < 4; i++)
        *(float4*)&ws32[wk][wns * 16 + i * 4] = make_float4(0.f, 0.f, 0.f, 0.f);
    }
    __syncthreads();
#pragma unroll
    for (int g = 0; g < 2; g++) {
      int kqq = rk0 + g;
      half8_t hv;
#pragma unroll
      for (int jj = 0; jj < 8; jj++) hv[jj] = (_Float16)ws32[kqq * 8 + jj][rn];
      *(half8_t*)&ws16[rn][kqq * 8] = hv;
    }
    __syncthreads();
    half8_t afrag[2];
#pragma unroll
    for (int i = 0; i < 2; i++)
      afrag[i] = *(const half8_t*)&as[w * 32 + i * 16 + lane16][kq * 8];
#pragma unroll
    for (int j = 0; j < 8; j++) {
      half8_t bfrag = *(const half8_t*)&ws16[j * 16 + lane16][kq * 8];
#pragma unroll
      for (int i = 0; i < 2; i++)
        acc[i][j] = __builtin_amdgcn_mfma_f32_16x16x32_f16(afrag[i], bfrag, acc[i][j], 0, 0, 0);
    }
    __syncthreads();
  }
#pragma unroll
  for (int j = 0; j < 8; j++) {
    int col = bn + j * 16 + lane16;
    float bv = bias[col];
#pragma unroll
    for (int i = 0; i < 2; i++) {
      int rbase = bm + w * 32 + i * 16 + kq * 4;
#pragma unroll
      for (int r = 0; r < 4; r++)
        C[(size_t)(rbase + r) * N + col] = __float2half(acc[i][j][r] + bv);
    }
  }
}

// ---------- MFMA LSTM step ----------
// Grid 128 x 256. Block bi = dir*64 + cblk; owns h-cols [cblk*8,+8) (32 z-cols),
// ALL 64 rows, full K=512 (no cross-block dependence within a step).
// Wave w = rows [w*16, w*16+16). LDS: h tile 64KB (XOR chunk swizzle) +
// U fp16 [32 c][528 k-stride] 33.8KB + z [64][33] 8.4KB = 107,776 B.
__global__ __launch_bounds__(256) void lstm_step_kernel(
    const __half* __restrict__ xzf, const __half* __restrict__ xzb,
    const float* __restrict__ Uf, const float* __restrict__ Ub,
    const int* __restrict__ text,
    const __half* __restrict__ hprev, __half* __restrict__ hnext,
    float* __restrict__ cbuf, int s,
    __half* __restrict__ hs_out, float* __restrict__ hT_out) {
  __shared__ __align__(16) _Float16 s_h[64 * 512];
  __shared__ __align__(16) _Float16 s_u[32 * 528];
  __shared__ __align__(16) float    s_z[64 * 33];

  const int t    = threadIdx.x;
  const int bi   = blockIdx.x;
  const int dir  = bi >> 6;
  const int cblk = bi & 63;
  const int hc0  = cblk * 8;
  const int tt   = dir ? (NS - 1 - s) : s;
  const __half* xz = dir ? xzb : xzf;
  const float* U = dir ? Ub : Uf;

  const int w    = t >> 6;
  const int lane = t & 63;
  const int l16  = lane & 15;
  const int quad = lane >> 4;

  f32x4_t acc[2] = {{0.f, 0.f, 0.f, 0.f}, {0.f, 0.f, 0.f, 0.f}};

  if (s > 0) {
    // stage h(s-1): 64 rows x 512 fp16; 16B chunk ch stored at ch^row
#pragma unroll
    for (int i = 0; i < 16; i++) {
      int e   = i * 256 + t;
      int row = e >> 6;
      int ch  = e & 63;
      *(uint4*)(s_h + row * 512 + (ch ^ row) * 8) =
          *(const uint4*)(hprev + (size_t)row * 1024 + dir * NH + ch * 8);
    }
    // stage U slice: thread t covers k rows {2t, 2t+1}, 32 cols; fp32->fp16,
    // layout s_u[c*528 + k] (write half2 along k -> ds_write_b32, conflict-free)
    {
      const float* u0 = U + (size_t)(2 * t) * N4H;
      float va[2][32];
#pragma unroll
      for (int g = 0; g < 4; g++) {
        *(float4*)&va[0][g * 8]     = *(const float4*)(u0 + g * NH + hc0);
        *(float4*)&va[0][g * 8 + 4] = *(const float4*)(u0 + g * NH + hc0 + 4);
        *(float4*)&va[1][g * 8]     = *(const float4*)(u0 + N4H + g * NH + hc0);
        *(float4*)&va[1][g * 8 + 4] = *(const float4*)(u0 + N4H + g * NH + hc0 + 4);
      }
#pragma unroll
      for (int c = 0; c < 32; c++) {
        union { _Float16 h[2]; unsigned u; } pk;
        pk.h[0] = (_Float16)va[0][c];
        pk.h[1] = (_Float16)va[1][c];
        *(unsigned*)(s_u + c * 528 + 2 * t) = pk.u;
      }
    }
    __syncthreads();
    // MFMA: rows w*16.., z-cols nt*16+l16, K=512
    const int r = w * 16 + l16;
#pragma unroll
    for (int kt = 0; kt < 16; kt++) {
      int chunk = (kt * 4 + quad) ^ r;
      half8_t af = *(const half8_t*)(s_h + r * 512 + chunk * 8);
      half8_t u0 = *(const half8_t*)(s_u + (l16) * 528 + kt * 32 + quad * 8);
      half8_t u1 = *(const half8_t*)(s_u + (16 + l16) * 528 + kt * 32 + quad * 8);
      acc[0] = __builtin_amdgcn_mfma_f32_16x16x32_f16(af, u0, acc[0], 0, 0, 0);
      acc[1] = __builtin_amdgcn_mfma_f32_16x16x32_f16(af, u1, acc[1], 0, 0, 0);
    }
  }

  // dump z = acc + xz into s_z[64][33]
  {
    int row0 = w * 16 + quad * 4;
#pragma unroll
    for (int nt = 0; nt < 2; nt++) {
      int c = nt * 16 + l16;
      int g = c >> 3, j = c & 7;
#pragma unroll
      for (int r4 = 0; r4 < 4; r4++) {
        int row = row0 + r4;
        float xzv = __half2float(xz[((size_t)row * NS + tt) * N4H + g * NH + hc0 + j]);
        s_z[row * 33 + c] = acc[nt][r4] + xzv;
      }
    }
  }
  __syncthreads();

  // gate update: 2 states per thread (512 states: 64 rows x 8 h-cols)
#pragma unroll
  for (int u = 0; u < 2; u++) {
    int idx = u * 256 + t;
    int row = idx >> 3, j = idx & 7;
    float zi = s_z[row * 33 + j];
    float zf = s_z[row * 33 + 8 + j];
    float zg = s_z[row * 33 + 16 + j];
    float zo = s_z[row * 33 + 24 + j];
    size_t gidx = (size_t)row * 1024 + dir * NH + hc0 + j;
    float cprev = (s > 0) ? cbuf[gidx] : 0.f;
    float hold  = (s > 0) ? (float)s_h[row * 512 + (cblk ^ row) * 8 + j] : 0.f;
    float ig = 1.f / (1.f + expf(-zi));
    float fg = 1.f / (1.f + expf(-zf));
    float gv = tanhf(zg);
    float og = 1.f / (1.f + expf(-zo));
    float cn = fg * cprev + ig * gv;
    float hn = og * tanhf(cn);
    bool m = text[row * NS + tt] != 0;
    float c = m ? cn : cprev;
    float h = m ? hn : hold;
    cbuf[gidx] = c;
    hnext[gidx] = __float2half(h);
    if (hs_out) hs_out[((size_t)row * NS + tt) * 1024 + dir * NH + hc0 + j] = __float2half(h);
    if (hT_out && s == NS - 1) hT_out[gidx] = h;
  }
}

// ---------- fp32 SMEM GEMM (head only) ----------
template <int ACT>
__global__ __launch_bounds__(256) void gemm_kernel(
    const float* __restrict__ A, const float* __restrict__ W,
    const float* __restrict__ bias, float* __restrict__ C,
    int M, int N, int K) {
  __shared__ __align__(16) float As[8][128];
  __shared__ __align__(16) float Bs[8][128];
  const int t  = threadIdx.x;
  const int bn = blockIdx.x * 128;
  const int bm = blockIdx.y * 128;
  const int tx = t & 15, ty = t >> 4;
  const int lm  = t >> 1;
  const int lk4 = (t & 1) * 4;
  const int lbk = t >> 5;
  const int lbn = (t & 31) * 4;
  float acc[8][8];
#pragma unroll
  for (int i = 0; i < 8; i++)
#pragma unroll
    for (int j = 0; j < 8; j++) acc[i][j] = 0.f;

  for (int k0 = 0; k0 < K; k0 += 8) {
#pragma unroll
    for (int i = 0; i < 4; i++) {
      int k = k0 + lk4 + i;
      int m = bm + lm;
      float v = 0.f;
      if (k < K && m < M) v = A[(size_t)m * K + k];
      As[lk4 + i][lm] = v;
    }
    {
      int k = k0 + lbk;
      float4 v = make_float4(0.f, 0.f, 0.f, 0.f);
      if (k < K) v = *(const float4*)(W + (size_t)k * N + bn + lbn);
      *(float4*)(&Bs[lbk][lbn]) = v;
    }
    __syncthreads();
#pragma unroll
    for (int kk = 0; kk < 8; kk++) {
      float a[8], b[8];
      *(float4*)(a)     = *(const float4*)(&As[kk][ty * 8]);
      *(float4*)(a + 4) = *(const float4*)(&As[kk][ty * 8 + 4]);
      *(float4*)(b)     = *(const float4*)(&Bs[kk][tx * 8]);
      *(float4*)(b + 4) = *(const float4*)(&Bs[kk][tx * 8 + 4]);
#pragma unroll
      for (int i = 0; i < 8; i++)
#pragma unroll
        for (int j = 0; j < 8; j++) acc[i][j] += a[i] * b[j];
    }
    __syncthreads();
  }
  float4 bv0 = *(const float4*)(bias + bn + tx * 8);
  float4 bv1 = *(const float4*)(bias + bn + tx * 8 + 4);
#pragma unroll
  for (int i = 0; i < 8; i++) {
    int m = bm + ty * 8 + i;
    if (m >= M) continue;
    float4 o0, o1;
    o0.x = acc[i][0] + bv0.x; o0.y = acc[i][1] + bv0.y;
    o0.z = acc[i][2] + bv0.z; o0.w = acc[i][3] + bv0.w;
    o1.x = acc[i][4] + bv1.x; o1.y = acc[i][5] + bv1.y;
    o1.z = acc[i][6] + bv1.z; o1.w = acc[i][7] + bv1.w;
    if (ACT == 1) {
      o0.x = o0.x >= 0.f ? o0.x : 0.2f * o0.x;  o0.y = o0.y >= 0.f ? o0.y : 0.2f * o0.y;
      o0.z = o0.z >= 0.f ? o0.z : 0.2f * o0.z;  o0.w = o0.w >= 0.f ? o0.w : 0.2f * o0.w;
      o1.x = o1.x >= 0.f ? o1.x : 0.2f * o1.x;  o1.y = o1.y >= 0.f ? o1.y : 0.2f * o1.y;
      o1.z = o1.z >= 0.f ? o1.z : 0.2f * o1.z;  o1.w = o1.w >= 0.f ? o1.w : 0.2f * o1.w;
    }
    *(float4*)(C + (size_t)m * N + bn + tx * 8)     = o0;
    *(float4*)(C + (size_t)m * N + bn + tx * 8 + 4) = o1;
  }
}

__global__ void final_kernel(const float* __restrict__ a1, const float* __restrict__ w,
                             const float* __restrict__ bias, float* __restrict__ out) {
  const int b = blockIdx.x, t = threadIdx.x;
  float v = a1[b * 256 + t] * w[t];
#pragma unroll
  for (int off = 32; off > 0; off >>= 1) v += __shfl_down(v, off, 64);
  __shared__ float red[4];
  if ((t & 63) == 0) red[t >> 6] = v;
  __syncthreads();
  if (t == 0) out[b] = (red[0] + red[1]) + (red[2] + red[3]) + bias[0];
}

extern "C" void kernel_launch(void* const* d_in, const int* in_sizes, int n_in,
                              void* d_out, int out_size, void* d_ws, size_t ws_size,
                              hipStream_t stream) {
  const int*   text = (const int*)  d_in[0];
  const float* emb  = (const float*)d_in[1];
  const float* W0f  = (const float*)d_in[2];
  const float* U0f  = (const float*)d_in[3];
  const float* b0f  = (const float*)d_in[4];
  const float* W0b  = (const float*)d_in[5];
  const float* U0b  = (const float*)d_in[6];
  const float* b0b  = (const float*)d_in[7];
  const float* W1f  = (const float*)d_in[8];
  const float* U1f  = (const float*)d_in[9];
  const float* b1f  = (const float*)d_in[10];
  const float* W1b  = (const float*)d_in[11];
  const float* U1b  = (const float*)d_in[12];
  const float* b1b  = (const float*)d_in[13];
  const float* d0w  = (const float*)d_in[14];
  const float* d0b  = (const float*)d_in[15];
  const float* d1w  = (const float*)d_in[16];
  const float* d1b  = (const float*)d_in[17];
  const float* d2w  = (const float*)d_in[18];
  const float* d2b  = (const float*)d_in[19];
  float* out = (float*)d_out;

  // workspace carve: identical to R4/R6 proven footprint (168,955,904 B)
  char* p = (char*)d_ws;
  __half* xzA = (__half*)p;  p += (size_t)NB * NS * N4H * 2;
  __half* xzB = (__half*)p;  p += (size_t)NB * NS * N4H * 2;
  char* region1 = p;         p += (size_t)NB * NS * 1024 * 2;
  _Float16* x_emb = (_Float16*)region1;   // dead before hs0 written
  __half*   hs0   = (__half*)region1;
  __half* hp0  = (__half*)p;  p += 64 * 1024 * 2;
  __half* hp1  = (__half*)p;  p += 64 * 1024 * 2;
  float*  cbuf = (float*)p;   p += 64 * 1024 * 4;
  float*  feat = (float*)p;   p += 64 * 1024 * 4;
  float*  a0   = (float*)p;   p += 64 * 512 * 4;
  float*  a1   = (float*)p;   p += 64 * 256 * 4;

  hipLaunchKernelGGL(embed_f16_kernel, dim3(4096), dim3(256), 0, stream, text, emb, x_emb);

  dim3 gmf(16, 128);
  hipLaunchKernelGGL(gemm_mfma_kernel, gmf, dim3(256), 0, stream, x_emb, W0f, b0f, xzA, 16384, N4H, NDP, ND);
  hipLaunchKernelGGL(gemm_mfma_kernel, gmf, dim3(256), 0, stream, x_emb, W0b, b0b, xzB, 16384, N4H, NDP, ND);

  for (int s = 0; s < NS; s++) {
    const __half* hp = (s & 1) ? hp1 : hp0;
    __half*       hn = (s & 1) ? hp0 : hp1;
    lstm_step_kernel<<<dim3(128), dim3(256), 0, stream>>>(
        xzA, xzB, U0f, U0b, text, hp, hn, cbuf, s, hs0, (float*)nullptr);
  }

  hipLaunchKernelGGL(gemm_mfma_kernel, gmf, dim3(256), 0, stream, (const _Float16*)hs0, W1f, b1f, xzA, 16384, N4H, 1024, 1024);
  hipLaunchKernelGGL(gemm_mfma_kernel, gmf, dim3(256), 0, stream, (const _Float16*)hs0, W1b, b1b, xzB, 16384, N4H, 1024, 1024);

  for (int s = 0; s < NS; s++) {
    const __half* hp = (s & 1) ? hp1 : hp0;
    __half*       hn = (s & 1) ? hp0 : hp1;
    lstm_step_kernel<<<dim3(128), dim3(256), 0, stream>>>(
        xzA, xzB, U1f, U1b, text, hp, hn, cbuf, s, (__half*)nullptr, feat);
  }

  gemm_kernel<1><<<dim3(4, 1), dim3(256), 0, stream>>>(feat, d0w, d0b, a0, 64, 512, 1024);
  gemm_kernel<1><<<dim3(2, 1), dim3(256), 0, stream>>>(a0, d1w, d1b, a1, 64, 256, 512);
  hipLaunchKernelGGL(final_kernel, dim3(64), dim3(256), 0, stream, a1, d2w, d2b, out);
}